// Round 4
// baseline (107.300 us; speedup 1.0000x reference)
//
#include <hip/hip_runtime.h>
#include <math.h>

// Problem constants: B=32, C=256, H=W=56, group=4, d=1
constexpr int B_  = 32;
constexpr int C_  = 256;
constexpr int G_  = 4;
constexpr int K_  = 64;
constexpr int P_  = 3136;        // 56*56
constexpr int NB_ = 29;
constexpr int BG_ = 128;         // B*G
constexpr int CP_ = C_ * P_;
constexpr int N_  = B_ * CP_;
constexpr int N4_ = N_ / 4;
constexpr float TWO_PI = 6.283185307179586f;

// Radial bin label in RAW (unshifted) coords, p = kh*56 + kw.
// Symmetric under (kh,kw) swap, so any consistent row/col layout works.
__device__ __forceinline__ int lab_of(int p) {
    int h = p / 56, w = p - h * 56;
    int hh = ((h + 28) % 56) - 28;
    int ww = ((w + 28) % 56) - 28;
    int r2 = hh * hh + ww * ww;
    int rf = (int)sqrtf((float)r2);
    while ((rf + 1) * (rf + 1) <= r2) ++rf;
    while (rf * rf > r2) --rf;
    if (rf > 28) rf = 28;
    return rf;
}

// Kernel A: fused comp + row-DFT (F1). One block per (bg, 4 rows).
// tmpF[bg][kw][h] = sum_w comp[bg][h][w] e^{-2pi i w kw/56}
__global__ __launch_bounds__(256) void comp_f1_kernel(const float* __restrict__ feature,
                                                      float2* __restrict__ tmpF) {
    int blk = blockIdx.x, bg = blk / 14, rblk = blk - bg * 14, r0 = rblk * 4;
    int b = bg >> 2, g = bg & 3;
    int t = threadIdx.x;
    __shared__ float  sx[4][57];
    __shared__ float2 stw[56];
    if (t < 56) { float a = -TWO_PI * (float)t / 56.f; stw[t] = make_float2(cosf(a), sinf(a)); }
    if (t < 224) {
        const float* base = feature + (b * C_ + g * K_) * P_ + r0 * 56 + t;
        float sum = 0.f, mx = -INFINITY;
#pragma unroll 8
        for (int k = 0; k < K_; ++k) {
            float v = base[k * P_];
            sum += v;
            mx = fmaxf(mx, v);
        }
        sx[t / 56][t % 56] = sum * (1.f / 64.f) + mx;
    }
    __syncthreads();
    if (t < 224) {
        int r = t & 3, k = t >> 2;
        float sr = 0.f, si = 0.f; int idx = 0;
        for (int j = 0; j < 56; ++j) {
            float v = sx[r][j];
            float2 tw = stw[idx];
            sr = fmaf(v, tw.x, sr); si = fmaf(v, tw.y, si);
            idx += k; if (idx >= 56) idx -= 56;
        }
        tmpF[bg * P_ + k * 56 + (r0 + r)] = make_float2(sr, si);
    }
}

// Kernel B: whole mid-section for one plane per block.
// F2 (col DFT) -> |spec| radial bins (scan, no atomics) -> FC -> scale ->
// I1 (kh inverse DFT) -> I2 (kw inverse DFT, real) + plane min/max.
__global__ __launch_bounds__(1024, 1) void mid_kernel(const float2* __restrict__ tmpF,
                                                      const float* __restrict__ fc_w,
                                                      const float* __restrict__ fc_b,
                                                      float* __restrict__ nf,
                                                      float2* __restrict__ mnmx) {
    int bg = blockIdx.x, g = bg & 3;
    int t = threadIdx.x;
    __shared__ float2 bufA[56 * 57];        // [row][col] at row*57+col
    __shared__ float2 bufB[56 * 57];
    __shared__ float  amp[P_];              // |spec| at kw*56+kh
    __shared__ unsigned char slab[P_];      // radial label
    __shared__ float2 stwf[56], stwi[56];
    __shared__ float  part_s[NB_ * 33], part_c[NB_ * 33];
    __shared__ float  pooled_s[NB_], att_s[NB_];
    __shared__ float  red_mn[1024], red_mx[1024];

    if (t < 56) {
        float a = TWO_PI * (float)t / 56.f;
        stwf[t] = make_float2(cosf(a), -sinf(a));    // e^{-i}
        stwi[t] = make_float2(cosf(a),  sinf(a));    // e^{+i}
    }
    for (int i = t; i < P_; i += 1024) slab[i] = (unsigned char)lab_of(i);
    // load tmpF plane: [kw][h]
    for (int i = t; i < P_; i += 1024) {
        int r = i / 56, c = i - r * 56;
        bufA[r * 57 + c] = tmpF[bg * P_ + i];
    }
    __syncthreads();
    // F2: bufB[kw][kh] = sum_h bufA[kw][h] * e^{-2pi i h kh/56}
    for (int i = t; i < P_; i += 1024) {
        int kw = i / 56, kh = i - kw * 56;
        const float2* row = &bufA[kw * 57];
        float sr = 0.f, si = 0.f; int idx = 0;
        for (int j = 0; j < 56; ++j) {
            float2 a = row[j];
            float2 w = stwf[idx];
            sr = fmaf(a.x, w.x, fmaf(-a.y, w.y, sr));
            si = fmaf(a.x, w.y, fmaf( a.y, w.x, si));
            idx += kh; if (idx >= 56) idx -= 56;
        }
        bufB[kw * 57 + kh] = make_float2(sr, si);
        amp[i] = sqrtf(sr * sr + si * si);           // lab symmetric -> slab[i] ok
    }
    __syncthreads();
    // Radial bin sums + counts: 32 lanes per bin scan the plane. No atomics.
    if (t < NB_ * 32) {
        int bin = t >> 5, ln = t & 31;
        float s = 0.f, c = 0.f;
        for (int p = ln; p < P_; p += 32)
            if (slab[p] == (unsigned char)bin) { s += amp[p]; c += 1.f; }
        part_s[bin * 33 + ln] = s;
        part_c[bin * 33 + ln] = c;
    }
    __syncthreads();
    if (t < NB_) {
        float s = 0.f, c = 0.f;
        for (int j = 0; j < 32; ++j) { s += part_s[t * 33 + j]; c += part_c[t * 33 + j]; }
        pooled_s[t] = s / c;
    }
    __syncthreads();
    if (t < NB_) {
        float acc = fc_b[g * NB_ + t];
        const float* wrow = &fc_w[(g * NB_ + t) * NB_];
        for (int n = 0; n < NB_; ++n) acc = fmaf(pooled_s[n], wrow[n], acc);
        att_s[t] = acc >= 0.f ? acc : 0.01f * acc;
    }
    __syncthreads();
    // Scale spectrum in place by att[lab]
    for (int i = t; i < P_; i += 1024) {
        int kw = i / 56, kh = i - kw * 56;
        float a = att_s[slab[i]];
        float2 v = bufB[kw * 57 + kh];
        bufB[kw * 57 + kh] = make_float2(v.x * a, v.y * a);
    }
    __syncthreads();
    // I1: bufA[kw][h] = sum_kh bufB[kw][kh] * e^{+2pi i kh h/56}
    for (int i = t; i < P_; i += 1024) {
        int kw = i / 56, h = i - kw * 56;
        const float2* row = &bufB[kw * 57];
        float sr = 0.f, si = 0.f; int idx = 0;
        for (int j = 0; j < 56; ++j) {
            float2 a = row[j];
            float2 w = stwi[idx];
            sr = fmaf(a.x, w.x, fmaf(-a.y, w.y, sr));
            si = fmaf(a.x, w.y, fmaf( a.y, w.x, si));
            idx += h; if (idx >= 56) idx -= 56;
        }
        bufA[kw * 57 + h] = make_float2(sr, si);
    }
    __syncthreads();
    // I2: nf[h][w] = (1/P) Re sum_kw bufA[kw][h] e^{+2pi i kw w/56}; min/max.
    float lmn = INFINITY, lmx = -INFINITY;
    for (int i = t; i < P_; i += 1024) {
        int h = i / 56, w = i - h * 56;
        float sr = 0.f; int idx = 0;
        for (int j = 0; j < 56; ++j) {
            float2 a = bufA[j * 57 + h];
            float2 tw = stwi[idx];
            sr = fmaf(a.x, tw.x, fmaf(-a.y, tw.y, sr));
            idx += w; if (idx >= 56) idx -= 56;
        }
        float v = sr * (1.0f / (float)P_);
        nf[bg * P_ + i] = v;
        lmn = fminf(lmn, v); lmx = fmaxf(lmx, v);
    }
    red_mn[t] = lmn; red_mx[t] = lmx;
    __syncthreads();
    for (int off = 512; off > 0; off >>= 1) {
        if (t < off) {
            red_mn[t] = fminf(red_mn[t], red_mn[t + off]);
            red_mx[t] = fmaxf(red_mx[t], red_mx[t + off]);
        }
        __syncthreads();
    }
    if (t == 0) mnmx[bg] = make_float2(red_mn[0], red_mx[0]);
}

// Kernel C: out = feature + gamma[c] * feature * attn_map, float4.
__global__ __launch_bounds__(256) void final_kernel(const float* __restrict__ feature,
                                                    const float* __restrict__ gamma,
                                                    const float* __restrict__ nf,
                                                    const float2* __restrict__ mnmx,
                                                    float* __restrict__ out) {
    int i = blockIdx.x * 256 + threadIdx.x;      // over N4_ (exact)
    int b = i / (C_ * 784);
    int rem = i - b * (C_ * 784);
    int c = rem / 784;
    int p4 = rem - c * 784;
    int bg = (b << 2) | (c >> 6);
    float2 mm = mnmx[bg];
    float inv = 1.0f / (mm.y - mm.x);
    float4 f = ((const float4*)feature)[i];
    float4 v = ((const float4*)nf)[bg * 784 + p4];
    float gam = gamma[c];
    float4 o;
    o.x = f.x + gam * f.x * ((v.x - mm.x) * inv);
    o.y = f.y + gam * f.y * ((v.y - mm.x) * inv);
    o.z = f.z + gam * f.z * ((v.z - mm.x) * inv);
    o.w = f.w + gam * f.w * ((v.w - mm.x) * inv);
    ((float4*)out)[i] = o;
}

extern "C" void kernel_launch(void* const* d_in, const int* in_sizes, int n_in,
                              void* d_out, int out_size, void* d_ws, size_t ws_size,
                              hipStream_t stream) {
    const float* feature = (const float*)d_in[0];
    const float* gamma   = (const float*)d_in[1];
    const float* fc_w    = (const float*)d_in[2];
    const float* fc_b    = (const float*)d_in[3];

    float* ws = (float*)d_ws;
    float2* tmpF = (float2*)ws;                   // 401408 float2
    float*  nf   = ws + 802816;                   // 401408 floats
    float2* mnmx = (float2*)(ws + 1204224);       // 128 float2
    float*  out  = (float*)d_out;

    comp_f1_kernel<<<BG_ * 14, 256, 0, stream>>>(feature, tmpF);
    mid_kernel    <<<BG_, 1024, 0, stream>>>(tmpF, fc_w, fc_b, nf, mnmx);
    final_kernel  <<<N4_ / 256, 256, 0, stream>>>(feature, gamma, nf, mnmx, out);
}